// Round 15
// baseline (1729.823 us; speedup 1.0000x reference)
//
#include <hip/hip_runtime.h>
#include <math.h>

// T=1000, B=256, F_IN=13 x3 -> 39 features, H=100, gates r,z,n (3H=300), 20 classes
#define T_STEPS 1000
#define BATCH   256
#define FIN     13
#define XDIM    39
#define HDIM    100
#define NCLS    20
#define GI3     300

__device__ __forceinline__ float fast_sigmoid(float v) {
    return 1.f / (1.f + __expf(-v));
}
// DPP butterflies (pure VALU). Validated R9/R12/R14 (all passed correctness).
__device__ __forceinline__ float quad_xor1(float v) {
    return __int_as_float(__builtin_amdgcn_update_dpp(0, __float_as_int(v), 0xB1, 0xF, 0xF, true)); // [1,0,3,2]
}
__device__ __forceinline__ float quad_xor2(float v) {
    return __int_as_float(__builtin_amdgcn_update_dpp(0, __float_as_int(v), 0x4E, 0xF, 0xF, true)); // [2,3,0,1]
}
__device__ __forceinline__ float half_mir(float v) {   // lane ^ 7 within each 8
    return __int_as_float(__builtin_amdgcn_update_dpp(0, __float_as_int(v), 0x141, 0xF, 0xF, true));
}
__device__ __forceinline__ float4 ld4g(const float* s, int fo, int lim) {
    if (fo + 4 <= lim) return *(const float4*)(s + fo);
    float4 v = make_float4(0.f, 0.f, 0.f, 0.f);
    if (fo + 0 < lim) v.x = s[fo + 0];
    if (fo + 1 < lim) v.y = s[fo + 1];
    if (fo + 2 < lim) v.z = s[fo + 2];
    if (fo + 3 < lim) v.w = s[fo + 3];
    return v;
}

// ============================================================================
// Kernel 1 (v2): gi[b][lt][g] = b_ih[g] + W_ih[g,:] @ x[t0+lt,b,:].
// R14 lesson: per-step global x load + 2 barriers = HBM latency on the chain
// every iteration (480us). Fix: bulk-preload this block's 125 x-rows into LDS
// once, then a barrier-free compute loop. 150 threads x 2 gi-rows (80 weight
// VGPRs, inside the proven B=512 -> 128-VGPR contract).
// ============================================================================
__launch_bounds__(512, 2)
__global__ void gi_prepass(const float* __restrict__ mfcc0,
                           const float* __restrict__ mfcc1,
                           const float* __restrict__ mfcc2,
                           const float* __restrict__ W_ih,
                           const float* __restrict__ b_ih,
                           float* __restrict__ gi,
                           int t0, int ns, int stride)
{
    const int b   = blockIdx.x;
    const int tc  = blockIdx.y;               // 125-step slice
    const int tid = threadIdx.x;

    __shared__ __align__(16) float xs[125 * 40];   // 20 KB, stride-40 rows (pad=0)

    const int sbase  = tc * 125;
    const int scount = (sbase + 125 <= ns) ? 125 : (ns - sbase);

    // ---- bulk preload: x rows for all local steps (one-time, latency amortized) ----
    for (int idx = tid; idx < scount * 40; idx += 512) {
        const int t = idx / 40, f = idx % 40;
        float v = 0.f;
        if (f < XDIM) {
            const float* xsrc = (f < FIN) ? mfcc0 : (f < 2 * FIN ? mfcc1 : mfcc2);
            v = xsrc[((size_t)(t0 + sbase + t) * BATCH + b) * FIN + (f % FIN)];
        }
        xs[idx] = v;
    }
    __syncthreads();

    if (tid < 150) {
        const int g0 = tid, g1 = tid + 150;
        float4 w[20];
        const float* sA = W_ih + g0 * XDIM;
        const float* sB = W_ih + g1 * XDIM;
        #pragma unroll
        for (int i = 0; i < 9; ++i) {
            w[i]      = make_float4(sA[4*i], sA[4*i+1], sA[4*i+2], sA[4*i+3]);
            w[10 + i] = make_float4(sB[4*i], sB[4*i+1], sB[4*i+2], sB[4*i+3]);
        }
        w[9]  = make_float4(sA[36], sA[37], sA[38], 0.f);   // pairs with xs pad = 0
        w[19] = make_float4(sB[36], sB[37], sB[38], 0.f);
        const float bias0 = b_ih[g0], bias1 = b_ih[g1];

        for (int t = 0; t < scount; ++t) {
            const float4* X4 = (const float4*)&xs[t * 40];
            float a0=0,a1=0,a2=0,a3=0, c0=0,c1=0,c2=0,c3=0;
            #pragma unroll
            for (int i = 0; i < 10; ++i) {
                const float4 vv = X4[i];
                a0=fmaf(w[i].x,vv.x,a0);      a1=fmaf(w[i].y,vv.y,a1);
                a2=fmaf(w[i].z,vv.z,a2);      a3=fmaf(w[i].w,vv.w,a3);
                c0=fmaf(w[10+i].x,vv.x,c0);   c1=fmaf(w[10+i].y,vv.y,c1);
                c2=fmaf(w[10+i].z,vv.z,c2);   c3=fmaf(w[10+i].w,vv.w,c3);
            }
            const size_t row = ((size_t)b * stride + sbase + t) * GI3;
            gi[row + g0] = bias0 + ((a0+a1)+(a2+a3));
            gi[row + g1] = bias1 + ((c0+c1)+(c2+c3));
        }
    }
}

// ============================================================================
// Kernel 2 (v2): consumer-only GRU chunk. R14 lessons applied:
//  - gi staged through LDS in 8-step double-buffered tiles: bulk coalesced
//    float4 loads once per 8 steps -> vmcnt barrier drain hits 1 step in 8
//    (was: ~900cy HBM latency on EVERY step's critical path).
//  - balanced group->wave mapping 6/6/6/6/6/6/7/7: all 8 waves active ->
//    2 consumer waves per SIMD interleave to hide the per-step chain (was:
//    6.25 active waves; one SIMD had a single wave, chain fully exposed).
//    14 spare lanes duplicate groups with bit-identical arithmetic (benign).
// Everything else byte-identical to R14's validated chunk (passed).
// ============================================================================
#define LNTHR   512
#define SLDS8   20
#define HPAD8   160
#define TSTEP   8
#define STN     (BATCH * HDIM)

__launch_bounds__(LNTHR, 2)
__global__ void gru_chunk(const float* __restrict__ len0,
                          const float* __restrict__ W_hh,
                          const float* __restrict__ b_hh,
                          const float* __restrict__ W_out,
                          const float* __restrict__ b_out,
                          const float* __restrict__ gi,
                          float* __restrict__ st,     // [h | sum | mx] planes
                          int ns, int stride, int first, int last,
                          float* __restrict__ out)
{
    const int b   = blockIdx.x;
    const int tid = threadIdx.x;

    __shared__ __align__(16) float Vh[2][HPAD8];        // h: part p at [20p..20p+15]
    __shared__ __align__(16) float gt[2][TSTEP * GI3];  // gi tiles, 19.2 KB
    __shared__ float feat[2 * HDIM];

    // ---- balanced geometry: wave w owns groups [gb, gb+ng); lane part p ----
    const int wv = tid >> 6;
    const int gb = 6 * wv + ((wv == 7) ? 1 : 0);        // 0,6,12,18,24,30,36,43
    int G = gb + ((tid & 63) >> 3);
    if (G > 49) G = 49;                                 // dup lanes mirror group 49
    const int p  = tid & 7;
    const int j0 = 2 * G;                               // even -> float2-aligned
    const int j1 = j0 + 1;

    // ---- weights: 2 units x 3 gates x 16 cols = 24 float4 (96 floats) ----
    float4 w[24];
    {
        const int base = 16 * p;
        #pragma unroll
        for (int rr = 0; rr < 3; ++rr) {
            const float* sA = W_hh + (rr * HDIM + j0) * HDIM;
            const float* sB = W_hh + (rr * HDIM + j1) * HDIM;
            #pragma unroll
            for (int i = 0; i < 4; ++i) {
                const int c = base + 4 * i;
                float4 tA, tB;
                tA.x = (c + 0 < HDIM) ? sA[c + 0] : 0.f;
                tA.y = (c + 1 < HDIM) ? sA[c + 1] : 0.f;
                tA.z = (c + 2 < HDIM) ? sA[c + 2] : 0.f;
                tA.w = (c + 3 < HDIM) ? sA[c + 3] : 0.f;
                tB.x = (c + 0 < HDIM) ? sB[c + 0] : 0.f;
                tB.y = (c + 1 < HDIM) ? sB[c + 1] : 0.f;
                tB.z = (c + 2 < HDIM) ? sB[c + 2] : 0.f;
                tB.w = (c + 3 < HDIM) ? sB[c + 3] : 0.f;
                w[rr * 4 + i]      = tA;
                w[12 + rr * 4 + i] = tB;
            }
        }
    }
    const float bA0 = b_hh[j0], bA1 = b_hh[HDIM + j0], bA2 = b_hh[2 * HDIM + j0];
    const float bB0 = b_hh[j1], bB1 = b_hh[HDIM + j1], bB2 = b_hh[2 * HDIM + j1];

    // ---- state init/reload ----
    float hA, hB, sumA, sumB, mxA, mxB;
    if (first) {
        hA = hB = 0.f; sumA = sumB = 0.f; mxA = mxB = -INFINITY;
    } else {
        const float2 h2 = *(const float2*)&st[b * HDIM + j0];
        const float2 s2 = *(const float2*)&st[STN + b * HDIM + j0];
        const float2 m2 = *(const float2*)&st[2 * STN + b * HDIM + j0];
        hA = h2.x; hB = h2.y; sumA = s2.x; sumB = s2.y; mxA = m2.x; mxB = m2.y;
    }
    if (tid < HPAD8) { Vh[0][tid] = 0.f; Vh[1][tid] = 0.f; }
    __syncthreads();
    const int hdst = SLDS8 * (j0 >> 4) + (j0 & 15);
    if (!first && p == 0)
        *(float2*)&Vh[0][hdst] = make_float2(hA, hB);       // dup lanes: same value

    // ---- stage tile 0 into gt[0] ----
    {
        const float* src = gi + (size_t)b * stride * GI3;
        const int lim = ((ns < TSTEP) ? ns : TSTEP) * GI3;
        for (int i4 = tid; i4 < 600; i4 += LNTHR) {
            const int fo = i4 * 4;
            if (fo < lim) *(float4*)&gt[0][fo] = ld4g(src, fo, lim);
        }
    }
    __syncthreads();

    for (int lt = 0; lt < ns; ++lt) {
        const int cur = lt & 1;
        const int nxt = cur ^ 1;
        const int tb  = (lt >> 3) & 1;

        // ---- stage next 8-step tile (coalesced; drained once per 8 steps) ----
        if ((lt & 7) == 0) {
            const int nb = lt + TSTEP;
            int rem = (ns - nb) * GI3;
            if (rem > 0) {
                if (rem > TSTEP * GI3) rem = TSTEP * GI3;
                const float* src = gi + ((size_t)b * stride + nb) * GI3;
                for (int i4 = tid; i4 < 600; i4 += LNTHR) {
                    const int fo = i4 * 4;
                    if (fo < rem) *(float4*)&gt[tb ^ 1][fo] = ld4g(src, fo, rem);
                }
            }
        }

        // ---- gi reads: 3 b64 from LDS tile (conflict-free, group-broadcast) ----
        const float* grow = &gt[tb][(lt & 7) * GI3];
        const float2 gR = *(const float2*)&grow[j0];
        const float2 gZ = *(const float2*)&grow[HDIM + j0];
        const float2 gN = *(const float2*)&grow[2 * HDIM + j0];

        // ---- GEMV: 4 b128 reads (skewed, conflict-free), 2 units x 3 gates ----
        const float4* V4 = (const float4*)(Vh[cur] + SLDS8 * p);
        float a00=0,a01=0,a10=0,a11=0,a20=0,a21=0;
        float c00=0,c01=0,c10=0,c11=0,c20=0,c21=0;
        #pragma unroll
        for (int i = 0; i < 4; ++i) {
            const float4 vv = V4[i];
            a00=fmaf(w[i].x,   vv.x,a00); a01=fmaf(w[i].y,   vv.y,a01);
            a00=fmaf(w[i].z,   vv.z,a00); a01=fmaf(w[i].w,   vv.w,a01);
            a10=fmaf(w[4+i].x, vv.x,a10); a11=fmaf(w[4+i].y, vv.y,a11);
            a10=fmaf(w[4+i].z, vv.z,a10); a11=fmaf(w[4+i].w, vv.w,a11);
            a20=fmaf(w[8+i].x, vv.x,a20); a21=fmaf(w[8+i].y, vv.y,a21);
            a20=fmaf(w[8+i].z, vv.z,a20); a21=fmaf(w[8+i].w, vv.w,a21);
            c00=fmaf(w[12+i].x,vv.x,c00); c01=fmaf(w[12+i].y,vv.y,c01);
            c00=fmaf(w[12+i].z,vv.z,c00); c01=fmaf(w[12+i].w,vv.w,c01);
            c10=fmaf(w[16+i].x,vv.x,c10); c11=fmaf(w[16+i].y,vv.y,c11);
            c10=fmaf(w[16+i].z,vv.z,c10); c11=fmaf(w[16+i].w,vv.w,c11);
            c20=fmaf(w[20+i].x,vv.x,c20); c21=fmaf(w[20+i].y,vv.y,c21);
            c20=fmaf(w[20+i].z,vv.z,c20); c21=fmaf(w[20+i].w,vv.w,c21);
        }
        float sA0 = a00+a01, sA1 = a10+a11, sA2 = a20+a21;
        float sB0 = c00+c01, sB1 = c10+c11, sB2 = c20+c21;
        // ---- 8-lane butterfly: xor1, xor2 (quad DPP) + lane^7 (half mirror) ----
        sA0 += quad_xor1(sA0); sA1 += quad_xor1(sA1); sA2 += quad_xor1(sA2);
        sB0 += quad_xor1(sB0); sB1 += quad_xor1(sB1); sB2 += quad_xor1(sB2);
        sA0 += quad_xor2(sA0); sA1 += quad_xor2(sA1); sA2 += quad_xor2(sA2);
        sB0 += quad_xor2(sB0); sB1 += quad_xor2(sB1); sB2 += quad_xor2(sB2);
        sA0 += half_mir(sA0);  sA1 += half_mir(sA1);  sA2 += half_mir(sA2);
        sB0 += half_mir(sB0);  sB1 += half_mir(sB1);  sB2 += half_mir(sB2);
        // ---- gates + state update, fully in-register ----
        const float rA = fast_sigmoid(gR.x + sA0 + bA0);
        const float zA = fast_sigmoid(gZ.x + sA1 + bA1);
        const float nA = fmaf(2.f, fast_sigmoid(2.f * fmaf(rA, sA2 + bA2, gN.x)), -1.f);
        const float hvA = fmaf(zA, hA - nA, nA);            // (1-z)*n + z*h
        const float rB = fast_sigmoid(gR.y + sB0 + bB0);
        const float zB = fast_sigmoid(gZ.y + sB1 + bB1);
        const float nB = fmaf(2.f, fast_sigmoid(2.f * fmaf(rB, sB2 + bB2, gN.y)), -1.f);
        const float hvB = fmaf(zB, hB - nB, nB);
        hA = hvA; hB = hvB;
        sumA += hvA; mxA = fmaxf(mxA, hvA);
        sumB += hvB; mxB = fmaxf(mxB, hvB);
        if (p == 0)
            *(float2*)&Vh[nxt][hdst] = make_float2(hvA, hvB);  // dup lanes: same value
        __syncthreads();
    }

    if (!last) {
        if (p == 0) {
            *(float2*)&st[b * HDIM + j0]           = make_float2(hA, hB);
            *(float2*)&st[STN + b * HDIM + j0]     = make_float2(sumA, sumB);
            *(float2*)&st[2 * STN + b * HDIM + j0] = make_float2(mxA, mxB);
        }
        return;
    }

    // ---- pooling + output linear (last chunk only) ----
    if (p == 0) {
        const float il = 1.f / len0[b];
        feat[j0]        = sumA * il;
        feat[j1]        = sumB * il;
        feat[HDIM + j0] = mxA;
        feat[HDIM + j1] = mxB;
    }
    __syncthreads();

    if (tid < NCLS) {
        float acc = b_out[tid];
        #pragma unroll 4
        for (int k = 0; k < 2 * HDIM; ++k)
            acc = fmaf(W_out[tid * 2 * HDIM + k], feat[k], acc);
        out[b * NCLS + tid] = acc;
    }
}

// ============================================================================
// Fallback: R9 kernel verbatim (735 us proven) — used when ws is too small.
// ============================================================================
#define NCONS   448
#define NTHR    640
#define HPAD    112
#define PCOLS   28

__attribute__((amdgpu_flat_work_group_size(NTHR, NTHR), amdgpu_waves_per_eu(2, 3)))
__global__ void gru_persistent(const float* __restrict__ mfcc0,
                               const float* __restrict__ mfcc1,
                               const float* __restrict__ mfcc2,
                               const float* __restrict__ len0,
                               const float* __restrict__ W_ih,
                               const float* __restrict__ W_hh,
                               const float* __restrict__ b_ih,
                               const float* __restrict__ b_hh,
                               const float* __restrict__ W_out,
                               const float* __restrict__ b_out,
                               float* __restrict__ out)
{
    const int b   = blockIdx.x;
    const int tid = threadIdx.x;

    __shared__ __align__(16) float Vh[2][HPAD];
    __shared__ __align__(16) float gib[2][4 * HDIM];
    __shared__ __align__(16) float xbuf[2][40];
    __shared__ float feat[2 * HDIM];

    const bool isCons = (tid < NCONS);
    const int q  = tid >> 2;
    const int p  = tid & 3;
    const int j  = (q < HDIM) ? q : (HDIM - 1);
    const int q0 = isCons ? 0 : (tid - NCONS);
    const int gA = 2 * ((q0 < 150) ? q0 : 149);
    const int gB = gA + 1;

    float4 w[21];
    float  bh0 = 0.f, bh1 = 0.f, bh2 = 0.f;
    int    ofA = 0, ofB = 0;
    if (isCons) {
        const int base = PCOLS * p;
        #pragma unroll
        for (int rr = 0; rr < 3; ++rr) {
            const float* src = W_hh + (rr * HDIM + j) * HDIM;
            #pragma unroll
            for (int i = 0; i < 7; ++i) {
                const int c = base + 4 * i;
                float4 t;
                t.x = (c + 0 < HDIM) ? src[c + 0] : 0.f;
                t.y = (c + 1 < HDIM) ? src[c + 1] : 0.f;
                t.z = (c + 2 < HDIM) ? src[c + 2] : 0.f;
                t.w = (c + 3 < HDIM) ? src[c + 3] : 0.f;
                w[rr * 7 + i] = t;
            }
        }
        bh0 = b_hh[j]; bh1 = b_hh[HDIM + j]; bh2 = b_hh[2 * HDIM + j];
    } else {
        const float* sA = W_ih + gA * XDIM;
        const float* sB = W_ih + gB * XDIM;
        #pragma unroll
        for (int i = 0; i < 9; ++i) {
            w[i]      = make_float4(sA[4*i], sA[4*i+1], sA[4*i+2], sA[4*i+3]);
            w[10 + i] = make_float4(sB[4*i], sB[4*i+1], sB[4*i+2], sB[4*i+3]);
        }
        w[9]  = make_float4(sA[36], sA[37], sA[38], 0.f);
        w[19] = make_float4(sB[36], sB[37], sB[38], 0.f);
        w[20] = make_float4(0, 0, 0, 0);
        bh0 = b_ih[gA]; bh1 = b_ih[gB];
        ofA = (gA % HDIM) * 4 + gA / HDIM;
        ofB = (gB % HDIM) * 4 + gB / HDIM;
    }

    const float* xsrc = mfcc0;
    int xoff = b * FIN;
    if (!isCons && q0 < XDIM) {
        const int f = q0 % FIN;
        xsrc = (q0 < FIN) ? mfcc0 : (q0 < 2 * FIN ? mfcc1 : mfcc2);
        xoff = b * FIN + f;
    }

    if (tid < HPAD) { Vh[0][tid] = 0.f; Vh[1][tid] = 0.f; }
    if (tid < 40) {
        float v0 = 0.f, v1 = 0.f;
        if (tid < XDIM) {
            const int f = tid % FIN;
            const float* xs = (tid < FIN) ? mfcc0 : (tid < 2 * FIN ? mfcc1 : mfcc2);
            v0 = xs[b * FIN + f];
            v1 = xs[(size_t)BATCH * FIN + b * FIN + f];
        }
        xbuf[0][tid] = v0; xbuf[1][tid] = v1;
    }
    __syncthreads();
    if (!isCons && q0 < 150) {
        const float4* X4 = (const float4*)xbuf[0];
        float a0=0,a1=0,a2=0,a3=0, c0=0,c1=0,c2=0,c3=0;
        #pragma unroll
        for (int i = 0; i < 10; ++i) {
            const float4 vv = X4[i];
            a0=fmaf(w[i].x,vv.x,a0);      a1=fmaf(w[i].y,vv.y,a1);
            a2=fmaf(w[i].z,vv.z,a2);      a3=fmaf(w[i].w,vv.w,a3);
            c0=fmaf(w[10+i].x,vv.x,c0);   c1=fmaf(w[10+i].y,vv.y,c1);
            c2=fmaf(w[10+i].z,vv.z,c2);   c3=fmaf(w[10+i].w,vv.w,c3);
        }
        gib[0][ofA] = bh0 + ((a0+a1)+(a2+a3));
        gib[0][ofB] = bh1 + ((c0+c1)+(c2+c3));
    }
    __syncthreads();

    float hreg = 0.f;
    float sum = 0.f, mx = -INFINITY;

    for (int t = 0; t < T_STEPS; ++t) {
        const int cur = t & 1;
        const int nxt = cur ^ 1;

        if (isCons) {
            const float4 g4 = ((const float4*)gib[cur])[j];
            const float4* V4 = (const float4*)(Vh[cur] + p * PCOLS);
            float a0=0,a1=0,a2=0,a3=0, b0=0,b1=0,b2=0,b3=0, c0=0,c1=0,c2=0,c3=0;
            #pragma unroll
            for (int i = 0; i < 7; ++i) {
                const float4 vv = V4[i];
                a0=fmaf(w[i].x,vv.x,a0);      a1=fmaf(w[i].y,vv.y,a1);
                a2=fmaf(w[i].z,vv.z,a2);      a3=fmaf(w[i].w,vv.w,a3);
                b0=fmaf(w[7+i].x,vv.x,b0);    b1=fmaf(w[7+i].y,vv.y,b1);
                b2=fmaf(w[7+i].z,vv.z,b2);    b3=fmaf(w[7+i].w,vv.w,b3);
                c0=fmaf(w[14+i].x,vv.x,c0);   c1=fmaf(w[14+i].y,vv.y,c1);
                c2=fmaf(w[14+i].z,vv.z,c2);   c3=fmaf(w[14+i].w,vv.w,c3);
            }
            float s0 = (a0+a1)+(a2+a3);
            float s1 = (b0+b1)+(b2+b3);
            float s2 = (c0+c1)+(c2+c3);
            s0 += quad_xor1(s0); s1 += quad_xor1(s1); s2 += quad_xor1(s2);
            s0 += quad_xor2(s0); s1 += quad_xor2(s1); s2 += quad_xor2(s2);
            const float rg = fast_sigmoid(g4.x + s0 + bh0);
            const float zg = fast_sigmoid(g4.y + s1 + bh1);
            const float na = fmaf(rg, s2 + bh2, g4.z);
            const float ng = fmaf(2.f, fast_sigmoid(2.f * na), -1.f);
            const float hv = fmaf(zg, hreg - ng, ng);
            hreg = hv;
            sum += hv; mx = fmaxf(mx, hv);
            if (p == 0 && q < HDIM) Vh[nxt][q] = hv;
        } else {
            float xv = 0.f;
            const bool doX = (q0 < XDIM) && (t + 2 < T_STEPS);
            if (doX) xv = xsrc[(size_t)(t + 2) * (BATCH * FIN) + xoff];
            if ((t + 1 < T_STEPS) && q0 < 150) {
                const float4* X4 = (const float4*)xbuf[nxt];
                float a0=0,a1=0,a2=0,a3=0, c0=0,c1=0,c2=0,c3=0;
                #pragma unroll
                for (int i = 0; i < 10; ++i) {
                    const float4 vv = X4[i];
                    a0=fmaf(w[i].x,vv.x,a0);      a1=fmaf(w[i].y,vv.y,a1);
                    a2=fmaf(w[i].z,vv.z,a2);      a3=fmaf(w[i].w,vv.w,a3);
                    c0=fmaf(w[10+i].x,vv.x,c0);   c1=fmaf(w[10+i].y,vv.y,c1);
                    c2=fmaf(w[10+i].z,vv.z,c2);   c3=fmaf(w[10+i].w,vv.w,c3);
                }
                gib[nxt][ofA] = bh0 + ((a0+a1)+(a2+a3));
                gib[nxt][ofB] = bh1 + ((c0+c1)+(c2+c3));
            }
            if (doX) xbuf[cur][q0] = xv;
        }
        __syncthreads();
    }

    if (isCons && p == 0 && q < HDIM) {
        feat[q]        = sum / len0[b];
        feat[HDIM + q] = mx;
    }
    __syncthreads();

    if (tid < NCLS) {
        float acc = b_out[tid];
        #pragma unroll 4
        for (int k = 0; k < 2 * HDIM; ++k)
            acc = fmaf(W_out[tid * 2 * HDIM + k], feat[k], acc);
        out[b * NCLS + tid] = acc;
    }
}

extern "C" void kernel_launch(void* const* d_in, const int* in_sizes, int n_in,
                              void* d_out, int out_size, void* d_ws, size_t ws_size,
                              hipStream_t stream)
{
    const float* mfcc0 = (const float*)d_in[0];
    const float* mfcc1 = (const float*)d_in[1];
    const float* mfcc2 = (const float*)d_in[2];
    const float* len0  = (const float*)d_in[3];
    const float* W_ih  = (const float*)d_in[4];
    const float* W_hh  = (const float*)d_in[5];
    const float* b_ih  = (const float*)d_in[6];
    const float* b_hh  = (const float*)d_in[7];
    const float* W_out = (const float*)d_in[8];
    const float* b_out = (const float*)d_in[9];
    float* out = (float*)d_out;

    const size_t step_bytes  = (size_t)BATCH * GI3 * sizeof(float);   // 307.2 KB/step
    const size_t state_bytes = 3u * BATCH * HDIM * sizeof(float);     // 307.2 KB
    int t_chunk = 0;
    if (d_ws != nullptr && ws_size > state_bytes + 16) {
        const size_t gi_budget = ws_size - state_bytes - 16;
        size_t tc = gi_budget / step_bytes;
        if (tc > T_STEPS) tc = T_STEPS;
        t_chunk = (int)(tc & ~(size_t)7);     // multiple of 8 for tile staging
    }

    if (t_chunk >= 104) {
        float* gi_ws = (float*)d_ws;
        float* st    = (float*)((char*)d_ws + ((ws_size - state_bytes) & ~(size_t)15));
        const int nch = (T_STEPS + t_chunk - 1) / t_chunk;
        for (int c = 0; c < nch; ++c) {
            const int t0 = c * t_chunk;
            const int ns = (t0 + t_chunk <= T_STEPS) ? t_chunk : (T_STEPS - t0);
            dim3 g1(BATCH, (ns + 124) / 125);
            gi_prepass<<<g1, 512, 0, stream>>>(mfcc0, mfcc1, mfcc2, W_ih, b_ih,
                                               gi_ws, t0, ns, t_chunk);
            gru_chunk<<<BATCH, LNTHR, 0, stream>>>(len0, W_hh, b_hh, W_out, b_out,
                                                   gi_ws, st, ns, t_chunk,
                                                   (c == 0) ? 1 : 0,
                                                   (c == nch - 1) ? 1 : 0, out);
        }
    } else {
        gru_persistent<<<BATCH, NTHR, 0, stream>>>(
            mfcc0, mfcc1, mfcc2, len0, W_ih, W_hh, b_ih, b_hh, W_out, b_out, out);
    }
}

// Round 16
// 741.114 us; speedup vs baseline: 2.3341x; 2.3341x over previous
//
#include <hip/hip_runtime.h>
#include <math.h>

// T=1000, B=256, F_IN=13 x3 -> 39 features, H=100, gates r,z,n (3H=300), 20 classes
#define T_STEPS 1000
#define BATCH   256
#define FIN     13
#define XDIM    39
#define HDIM    100
#define NCLS    20

#define NCONS   448     // 7 consumer waves: quad per hidden unit, 4 col-parts/lane
#define NTHR    640     // + 3 producer waves (192 threads, 150 active)
#define HPAD    112     // h padded to 4*28 for uniform float4 reads
#define PCOLS   28      // columns per lane part

__device__ __forceinline__ float fast_sigmoid(float v) {
    return 1.f / (1.f + __expf(-v));
}
// quad_perm butterflies (VALU DPP; all 4 quad lanes active in consumer waves)
__device__ __forceinline__ float quad_xor1(float v) {
    return __int_as_float(__builtin_amdgcn_update_dpp(0, __float_as_int(v), 0xB1, 0xF, 0xF, true)); // [1,0,3,2]
}
__device__ __forceinline__ float quad_xor2(float v) {
    return __int_as_float(__builtin_amdgcn_update_dpp(0, __float_as_int(v), 0x4E, 0xF, 0xF, true)); // [2,3,0,1]
}

// R13-R15 lesson: the consumer-only 2-kernel pipeline is chain-bound at ~2000
// cy/step (per-SIMD issue only ~37%; LDS-staging of gi made it WORSE) — the
// R9 producer/consumer overlap is load-bearing. This round: R9 byte-for-byte
// (735us proven) + ONE variable: T5 s_setprio — consumer waves (critical
// recurrence chain) at priority 1, producer waves at 0. On SIMDs hosting both,
// the scheduler prefers the critical wave; producers fill its stall cycles.
// T5 pays only with wave role-diversity (attn +4-7%), which R9 has.
__attribute__((amdgpu_flat_work_group_size(NTHR, NTHR), amdgpu_waves_per_eu(2, 3)))
__global__ void gru_persistent(const float* __restrict__ mfcc0,
                               const float* __restrict__ mfcc1,
                               const float* __restrict__ mfcc2,
                               const float* __restrict__ len0,
                               const float* __restrict__ W_ih,
                               const float* __restrict__ W_hh,
                               const float* __restrict__ b_ih,
                               const float* __restrict__ b_hh,
                               const float* __restrict__ W_out,
                               const float* __restrict__ b_out,
                               float* __restrict__ out)
{
    const int b   = blockIdx.x;
    const int tid = threadIdx.x;

    __shared__ __align__(16) float Vh[2][HPAD];       // h(t), pads [100..112) stay 0
    __shared__ __align__(16) float gib[2][4 * HDIM];  // gi transposed: [j][r,z,n,pad]
    __shared__ __align__(16) float xbuf[2][40];       // x staging (39 + zero pad)
    __shared__ float feat[2 * HDIM];

    const bool isCons = (tid < NCONS);

    // ---- consumer geometry: quad q = hidden unit j, lane part p ----
    const int q  = tid >> 2;                    // 0..111 (consumers), idle q>=100
    const int p  = tid & 3;                     // column part
    const int j  = (q < HDIM) ? q : (HDIM - 1); // clamped unit id

    // ---- producer geometry: rows (gA, gA+1) of the 300 gi rows ----
    const int q0 = isCons ? 0 : (tid - NCONS);  // 0..191, active <150
    const int gA = 2 * ((q0 < 150) ? q0 : 149);
    const int gB = gA + 1;

    // ---- SHARED weight registers: consumers w[0..20], producers w[0..19] ----
    float4 w[21];
    float  bh0 = 0.f, bh1 = 0.f, bh2 = 0.f;     // consumer: b_hh triple; producer: b_ih pair
    int    ofA = 0, ofB = 0;                    // producer gib write offsets
    if (isCons) {
        const int base = PCOLS * p;
        #pragma unroll
        for (int rr = 0; rr < 3; ++rr) {
            const float* src = W_hh + (rr * HDIM + j) * HDIM;
            #pragma unroll
            for (int i = 0; i < 7; ++i) {
                const int c = base + 4 * i;
                float4 t;
                t.x = (c + 0 < HDIM) ? src[c + 0] : 0.f;
                t.y = (c + 1 < HDIM) ? src[c + 1] : 0.f;
                t.z = (c + 2 < HDIM) ? src[c + 2] : 0.f;
                t.w = (c + 3 < HDIM) ? src[c + 3] : 0.f;
                w[rr * 7 + i] = t;
            }
        }
        bh0 = b_hh[j]; bh1 = b_hh[HDIM + j]; bh2 = b_hh[2 * HDIM + j];
        __builtin_amdgcn_s_setprio(1);          // critical-chain waves win arbitration
    } else {
        const float* sA = W_ih + gA * XDIM;
        const float* sB = W_ih + gB * XDIM;
        #pragma unroll
        for (int i = 0; i < 9; ++i) {
            w[i]      = make_float4(sA[4*i], sA[4*i+1], sA[4*i+2], sA[4*i+3]);
            w[10 + i] = make_float4(sB[4*i], sB[4*i+1], sB[4*i+2], sB[4*i+3]);
        }
        w[9]  = make_float4(sA[36], sA[37], sA[38], 0.f);   // pairs with xbuf[39]=0
        w[19] = make_float4(sB[36], sB[37], sB[38], 0.f);
        w[20] = make_float4(0, 0, 0, 0);
        bh0 = b_ih[gA]; bh1 = b_ih[gB];
        ofA = (gA % HDIM) * 4 + gA / HDIM;
        ofB = (gB % HDIM) * 4 + gB / HDIM;
    }

    // ---- producer x streaming source ----
    const float* xsrc = mfcc0;
    int xoff = b * FIN;
    if (!isCons && q0 < XDIM) {
        const int f = q0 % FIN;
        xsrc = (q0 < FIN) ? mfcc0 : (q0 < 2 * FIN ? mfcc1 : mfcc2);
        xoff = b * FIN + f;
    }

    // ---- prologue: h0 = 0 (both buffers, pads included), stage x(0)/x(1), gi(0) ----
    if (tid < HPAD) { Vh[0][tid] = 0.f; Vh[1][tid] = 0.f; }
    if (tid < 40) {
        float v0 = 0.f, v1 = 0.f;
        if (tid < XDIM) {
            const int f = tid % FIN;
            const float* xs = (tid < FIN) ? mfcc0 : (tid < 2 * FIN ? mfcc1 : mfcc2);
            v0 = xs[b * FIN + f];
            v1 = xs[(size_t)BATCH * FIN + b * FIN + f];
        }
        xbuf[0][tid] = v0; xbuf[1][tid] = v1;
    }
    __syncthreads();
    if (!isCons && q0 < 150) {
        const float4* X4 = (const float4*)xbuf[0];
        float a0=0,a1=0,a2=0,a3=0, c0=0,c1=0,c2=0,c3=0;
        #pragma unroll
        for (int i = 0; i < 10; ++i) {
            const float4 vv = X4[i];
            a0=fmaf(w[i].x,vv.x,a0);      a1=fmaf(w[i].y,vv.y,a1);
            a2=fmaf(w[i].z,vv.z,a2);      a3=fmaf(w[i].w,vv.w,a3);
            c0=fmaf(w[10+i].x,vv.x,c0);   c1=fmaf(w[10+i].y,vv.y,c1);
            c2=fmaf(w[10+i].z,vv.z,c2);   c3=fmaf(w[10+i].w,vv.w,c3);
        }
        gib[0][ofA] = bh0 + ((a0+a1)+(a2+a3));
        gib[0][ofB] = bh1 + ((c0+c1)+(c2+c3));
    }
    __syncthreads();

    float hreg = 0.f;                 // h_j, kept in registers (all 4 quad lanes)
    float sum = 0.f, mx = -INFINITY;

    for (int t = 0; t < T_STEPS; ++t) {
        const int cur = t & 1;
        const int nxt = cur ^ 1;

        if (isCons) {
            // ---- gi read issued FIRST (in-order LDS returns -> ready early) ----
            const float4 g4 = ((const float4*)gib[cur])[j];        // (i_r, i_z, i_n, -)
            // ---- GEMV part: 7 bcast float4 reads, 3 gate rows x 28 cols ----
            const float4* V4 = (const float4*)(Vh[cur] + p * PCOLS);
            float a0=0,a1=0,a2=0,a3=0, b0=0,b1=0,b2=0,b3=0, c0=0,c1=0,c2=0,c3=0;
            #pragma unroll
            for (int i = 0; i < 7; ++i) {
                const float4 vv = V4[i];
                a0=fmaf(w[i].x,vv.x,a0);      a1=fmaf(w[i].y,vv.y,a1);
                a2=fmaf(w[i].z,vv.z,a2);      a3=fmaf(w[i].w,vv.w,a3);
                b0=fmaf(w[7+i].x,vv.x,b0);    b1=fmaf(w[7+i].y,vv.y,b1);
                b2=fmaf(w[7+i].z,vv.z,b2);    b3=fmaf(w[7+i].w,vv.w,b3);
                c0=fmaf(w[14+i].x,vv.x,c0);   c1=fmaf(w[14+i].y,vv.y,c1);
                c2=fmaf(w[14+i].z,vv.z,c2);   c3=fmaf(w[14+i].w,vv.w,c3);
            }
            float s0 = (a0+a1)+(a2+a3);
            float s1 = (b0+b1)+(b2+b3);
            float s2 = (c0+c1)+(c2+c3);
            // ---- quad butterfly (DPP, VALU pipe): all 4 lanes get full sums ----
            s0 += quad_xor1(s0); s1 += quad_xor1(s1); s2 += quad_xor1(s2);
            s0 += quad_xor2(s0); s1 += quad_xor2(s1); s2 += quad_xor2(s2);
            // ---- gates + state update, fully in-register ----
            const float rg = fast_sigmoid(g4.x + s0 + bh0);
            const float zg = fast_sigmoid(g4.y + s1 + bh1);
            const float na = fmaf(rg, s2 + bh2, g4.z);
            const float ng = fmaf(2.f, fast_sigmoid(2.f * na), -1.f); // tanh, no clamp
            const float hv = fmaf(zg, hreg - ng, ng);              // (1-z)*n + z*h
            hreg = hv;
            sum += hv; mx = fmaxf(mx, hv);
            if (p == 0 && q < HDIM) Vh[nxt][q] = hv;               // publish h(t+1)
        } else {
            // ---- producers: prefetch x(t+2), compute gi(t+1) into gib[nxt] ----
            float xv = 0.f;
            const bool doX = (q0 < XDIM) && (t + 2 < T_STEPS);
            if (doX) xv = xsrc[(size_t)(t + 2) * (BATCH * FIN) + xoff];
            if ((t + 1 < T_STEPS) && q0 < 150) {
                const float4* X4 = (const float4*)xbuf[nxt];
                float a0=0,a1=0,a2=0,a3=0, c0=0,c1=0,c2=0,c3=0;
                #pragma unroll
                for (int i = 0; i < 10; ++i) {
                    const float4 vv = X4[i];
                    a0=fmaf(w[i].x,vv.x,a0);      a1=fmaf(w[i].y,vv.y,a1);
                    a2=fmaf(w[i].z,vv.z,a2);      a3=fmaf(w[i].w,vv.w,a3);
                    c0=fmaf(w[10+i].x,vv.x,c0);   c1=fmaf(w[10+i].y,vv.y,c1);
                    c2=fmaf(w[10+i].z,vv.z,c2);   c3=fmaf(w[10+i].w,vv.w,c3);
                }
                gib[nxt][ofA] = bh0 + ((a0+a1)+(a2+a3));
                gib[nxt][ofB] = bh1 + ((c0+c1)+(c2+c3));
            }
            if (doX) xbuf[cur][q0] = xv;
        }
        __syncthreads();
    }

    // ---- pooling + output linear ----
    if (isCons && p == 0 && q < HDIM) {
        feat[q]        = sum / len0[b];
        feat[HDIM + q] = mx;
    }
    __syncthreads();

    if (tid < NCLS) {
        float acc = b_out[tid];
        #pragma unroll 4
        for (int k = 0; k < 2 * HDIM; ++k)
            acc = fmaf(W_out[tid * 2 * HDIM + k], feat[k], acc);
        out[b * NCLS + tid] = acc;
    }
}

extern "C" void kernel_launch(void* const* d_in, const int* in_sizes, int n_in,
                              void* d_out, int out_size, void* d_ws, size_t ws_size,
                              hipStream_t stream)
{
    const float* mfcc0 = (const float*)d_in[0];
    const float* mfcc1 = (const float*)d_in[1];
    const float* mfcc2 = (const float*)d_in[2];
    const float* len0  = (const float*)d_in[3];
    const float* W_ih  = (const float*)d_in[4];
    const float* W_hh  = (const float*)d_in[5];
    const float* b_ih  = (const float*)d_in[6];
    const float* b_hh  = (const float*)d_in[7];
    const float* W_out = (const float*)d_in[8];
    const float* b_out = (const float*)d_in[9];
    float* out = (float*)d_out;

    gru_persistent<<<BATCH, NTHR, 0, stream>>>(
        mfcc0, mfcc1, mfcc2, len0, W_ih, W_hh, b_ih, b_hh, W_out, b_out, out);
}